// Round 1
// baseline (2222.934 us; speedup 1.0000x reference)
//
#include <hip/hip_runtime.h>
#include <stdint.h>

#define D_IN   2048
#define D_SAE  32768
#define NROWS  4096
#define TOPK   64
#define CAND_CAP 256
#define CAND_TARGET 100

typedef __attribute__((ext_vector_type(4))) float f32x4;
typedef __attribute__((ext_vector_type(8))) short short8;
typedef __attribute__((ext_vector_type(4))) unsigned short u16x4;
typedef __attribute__((ext_vector_type(8))) unsigned short u16x8;

__device__ __forceinline__ unsigned short f2bf(float f){
  unsigned int u = __float_as_uint(f);
  u = (u + 0x7FFFu + ((u >> 16) & 1u)) >> 16;   // RNE
  return (unsigned short)u;
}
__device__ __forceinline__ float bf2f(unsigned short h){
  return __uint_as_float(((unsigned int)h) << 16);
}
__device__ __forceinline__ void async16(const unsigned short* g, unsigned short* l){
  __builtin_amdgcn_global_load_lds(
      (const __attribute__((address_space(1))) unsigned int*)g,
      (__attribute__((address_space(3))) unsigned int*)l,
      16, 0, 0);
}

// ---------------- prep: conversions + transpose ----------------
__global__ void k_conv_x(const float* __restrict__ x, const float* __restrict__ b_dec,
                         unsigned short* __restrict__ o){
  const int i = blockIdx.x*256 + threadIdx.x;            // f4 index, 2097152 total
  const f32x4 v = ((const f32x4*)x)[i];
  const f32x4 b = ((const f32x4*)b_dec)[i & (D_IN/4 - 1)];
  u16x4 r;
#pragma unroll
  for (int j=0;j<4;j++) r[j] = f2bf(v[j]-b[j]);
  ((u16x4*)o)[i] = r;
}

__global__ void k_conv_w(const float* __restrict__ wsrc, unsigned short* __restrict__ o){
  const int i = blockIdx.x*256 + threadIdx.x;            // 16777216 total
  const f32x4 v = ((const f32x4*)wsrc)[i];
  u16x4 r;
#pragma unroll
  for (int j=0;j<4;j++) r[j] = f2bf(v[j]);
  ((u16x4*)o)[i] = r;
}

__global__ void k_transpose(const float* __restrict__ wdec, unsigned short* __restrict__ wdt){
  __shared__ float tile[32][33];
  const int j0 = blockIdx.x*32;   // d_sae
  const int i0 = blockIdx.y*32;   // d_in
  const int r = threadIdx.x >> 5, c = threadIdx.x & 31;
#pragma unroll
  for (int a=0;a<4;a++) tile[r+8*a][c] = wdec[(size_t)(i0+r+8*a)*D_SAE + j0 + c];
  __syncthreads();
#pragma unroll
  for (int a=0;a<4;a++) wdt[(size_t)(j0+r+8*a)*D_IN + i0 + c] = f2bf(tile[c][r+8*a]);
}

// ---------------- encoder GEMM (bf16 MFMA, m97 structure) ----------------
// C[4096][32768] = A[4096][2048] * B[32768][2048]^T + b_enc ; 128x128 tile, BK=32
__global__ void __launch_bounds__(256) k_gemm(
    const unsigned short* __restrict__ A,
    const unsigned short* __restrict__ B,
    const float* __restrict__ b_enc,
    float* __restrict__ C)
{
  __shared__ unsigned short As[128*32];
  __shared__ unsigned short Bs[128*32];
  const int tid = threadIdx.x;
  const int w = tid >> 6, l = tid & 63;
  const int bm = blockIdx.y, bn = blockIdx.x;
  const size_t brow = (size_t)bm*128, bcol = (size_t)bn*128;
  const int wr = w >> 1, wc = w & 1;       // 2x2 waves, 64x64 each
  const int srow = tid >> 2;               // staging row 0..63 (+64 chunk 1)
  const int skk  = (tid & 3) * 8;          // staging k offset (bf16 elems)
  const int fr = l & 15, fq = l >> 4;
  f32x4 acc[4][4] = {};
  const unsigned short* Ab = A + (brow + srow)*D_IN + skk;
  const unsigned short* Bb = B + (bcol + srow)*D_IN + skk;
  for (int kt = 0; kt < D_IN; kt += 32){
    __syncthreads();
    async16(Ab + kt,                 &As[w*512]);
    async16(Ab + (size_t)64*D_IN+kt, &As[2048 + w*512]);
    async16(Bb + kt,                 &Bs[w*512]);
    async16(Bb + (size_t)64*D_IN+kt, &Bs[2048 + w*512]);
    __syncthreads();
    short8 af[4], bf[4];
#pragma unroll
    for (int m=0;m<4;m++) af[m] = *(const short8*)&As[(wr*64 + m*16 + fr)*32 + fq*8];
#pragma unroll
    for (int n=0;n<4;n++) bf[n] = *(const short8*)&Bs[(wc*64 + n*16 + fr)*32 + fq*8];
#pragma unroll
    for (int m=0;m<4;m++)
#pragma unroll
      for (int n=0;n<4;n++)
        asm("v_mfma_f32_16x16x32_bf16 %0, %1, %2, %0" : "+v"(acc[m][n]) : "v"(af[m]), "v"(bf[n]));
  }
  asm volatile("s_nop 7\n\ts_nop 7" ::: "memory");   // MFMA->VALU read hazard insurance
#pragma unroll
  for (int n=0;n<4;n++){
    const size_t col = bcol + wc*64 + n*16 + fr;
    const float be = b_enc[col];
#pragma unroll
    for (int m=0;m<4;m++){
      const size_t row0 = brow + wr*64 + m*16 + fq*4;
#pragma unroll
      for (int r=0;r<4;r++)
        C[(row0 + r)*D_SAE + col] = acc[m][n][r] + be;
    }
  }
}

// ---------------- per-row candidate filter (histogram top-~100) ----------------
__global__ void __launch_bounds__(256) k_topk(
    const float* __restrict__ P,
    float* __restrict__ cv, int* __restrict__ ci, int* __restrict__ cnt)
{
  __shared__ unsigned int hist[1024];
  __shared__ unsigned int tsuf[256];
  __shared__ int sbin;
  __shared__ unsigned int wcnt;
  const int n = blockIdx.x, t = threadIdx.x;
  for (int i=t;i<1024;i+=256) hist[i]=0u;
  if (t==0){ sbin = 0; wcnt = 0u; }
  __syncthreads();
  const f32x4* row = (const f32x4*)(P + (size_t)n * D_SAE);
#pragma unroll 4
  for (int i=0;i<32;i++){
    f32x4 v = row[t + 256*i];
#pragma unroll
    for (int j=0;j<4;j++){
      float f = v[j];
      if (f > 0.f){
        int b = (int)(f * 64.f); if (b > 1023) b = 1023;
        atomicAdd(&hist[b], 1u);
      }
    }
  }
  __syncthreads();
  const unsigned int h0=hist[4*t+0],h1=hist[4*t+1],h2=hist[4*t+2],h3=hist[4*t+3];
  tsuf[t] = h0+h1+h2+h3;
  __syncthreads();
  for (int off=1; off<256; off<<=1){           // inclusive suffix scan
    unsigned int v = tsuf[t] + ((t+off<256)? tsuf[t+off] : 0u);
    __syncthreads();
    tsuf[t] = v;
    __syncthreads();
  }
  const unsigned int nxt = (t<255)? tsuf[t+1] : 0u;
  const unsigned int s3 = h3 + nxt, s2 = h2+s3, s1 = h1+s2, s0 = h0+s1;
  int best = -1;
  if      (s3 >= CAND_TARGET) best = 4*t+3;
  else if (s2 >= CAND_TARGET) best = 4*t+2;
  else if (s1 >= CAND_TARGET) best = 4*t+1;
  else if (s0 >= CAND_TARGET) best = 4*t+0;
  if (best >= 0) atomicMax(&sbin, best);
  __syncthreads();
  const int bT = sbin;
#pragma unroll 4
  for (int i=0;i<32;i++){
    f32x4 v = row[t + 256*i];
#pragma unroll
    for (int j=0;j<4;j++){
      float f = v[j];
      if (f > 0.f){
        int b = (int)(f * 64.f); if (b > 1023) b = 1023;
        if (b >= bT){
          unsigned int pos = atomicAdd(&wcnt, 1u);
          if (pos < CAND_CAP){
            cv[(size_t)n*CAND_CAP + pos] = f;
            ci[(size_t)n*CAND_CAP + pos] = (t + 256*i)*4 + j;
          }
        }
      }
    }
  }
  __syncthreads();
  if (t==0) cnt[n] = (int)(wcnt < CAND_CAP ? wcnt : CAND_CAP);
}

// ---------------- exact f64 rescore + top-64 select ----------------
__global__ void __launch_bounds__(256) k_rescore(
    const float* __restrict__ x, const float* __restrict__ b_dec,
    const float* __restrict__ W, const float* __restrict__ b_enc,
    const int* __restrict__ ci, const int* __restrict__ cnt,
    float* __restrict__ sv, int* __restrict__ si)
{
  __shared__ float xa[D_IN];
  __shared__ double ex[CAND_CAP];
  __shared__ int   exi[CAND_CAP];
  const int n = blockIdx.x, t = threadIdx.x, w = t>>6, l = t&63;
  for (int i=t;i<D_IN;i+=256) xa[i] = x[(size_t)n*D_IN + i] - b_dec[i];
  for (int i=t;i<CAND_CAP;i+=256){ ex[i] = -1.0e300; exi[i] = 0x7FFFFFFF; }
  const int cn0 = cnt[n];
  const int cn = cn0 < CAND_CAP ? cn0 : CAND_CAP;
  __syncthreads();
  for (int c=w; c<cn; c+=4){
    const int idx = ci[(size_t)n*CAND_CAP + c];
    const float* wr = W + (size_t)idx * D_IN;
    double a = 0.0;
    for (int e=l; e<D_IN; e+=64) a += (double)xa[e] * (double)wr[e];
#pragma unroll
    for (int off=32; off>0; off>>=1) a += __shfl_down(a, off);
    if (l==0){ ex[c] = a + (double)b_enc[idx]; exi[c] = idx; }
  }
  __syncthreads();
  if (w==0){
    for (int k=0;k<TOPK;k++){
      double bv = -1.0e301; int bi = 0x7FFFFFFF; int bp = -1;
      for (int c=l; c<cn; c+=64){
        double v = ex[c]; int idx = exi[c];
        if (v > bv || (v == bv && idx < bi)){ bv = v; bi = idx; bp = c; }
      }
#pragma unroll
      for (int off=32; off>0; off>>=1){
        double ov = __shfl_down(bv, off);
        int    oi = __shfl_down(bi, off);
        int    op = __shfl_down(bp, off);
        if (ov > bv || (ov == bv && oi < bi)){ bv=ov; bi=oi; bp=op; }
      }
      bv = __shfl(bv, 0); bi = __shfl(bi, 0); bp = __shfl(bp, 0);
      if (l==0){
        sv[(size_t)n*TOPK + k] = (bp>=0) ? (float)bv : 0.f;
        si[(size_t)n*TOPK + k] = (bp>=0) ? bi : 0;
        if (bp>=0) ex[bp] = -1.0e302;
      }
    }
  }
}

// ---------------- h output: zero + scatter ----------------
__global__ void k_zero(f32x4* __restrict__ p){
  const size_t i = (size_t)blockIdx.x*256 + threadIdx.x;
  f32x4 z = {0.f,0.f,0.f,0.f};
  p[i] = z;
}
__global__ void k_scatter(const float* __restrict__ sv, const int* __restrict__ si,
                          float* __restrict__ h){
  const int t = blockIdx.x*256 + threadIdx.x;   // 262144
  const int n = t >> 6;
  const float v = sv[t];
  h[(size_t)n*D_SAE + si[t]] = v > 0.f ? v : 0.f;
}

// ---------------- sparse decode + per-row loss partial ----------------
__global__ void __launch_bounds__(256) k_decode(
    const float* __restrict__ sv, const int* __restrict__ si,
    const unsigned short* __restrict__ wdt, const float* __restrict__ b_dec,
    const float* __restrict__ x, float* __restrict__ xhat, double* __restrict__ part)
{
  __shared__ float vs[TOPK];
  __shared__ int   is_[TOPK];
  __shared__ float red[256];
  const int n = blockIdx.x, t = threadIdx.x;
  if (t < TOPK){
    float v = sv[(size_t)n*TOPK + t];
    vs[t] = v > 0.f ? v : 0.f;
    is_[t] = si[(size_t)n*TOPK + t];
  }
  __syncthreads();
  const int i0 = t*8;
  float acc[8];
#pragma unroll
  for (int j=0;j<8;j++) acc[j] = b_dec[i0+j];
  for (int k=0;k<TOPK;k++){
    const float v = vs[k];
    const u16x8 wv = *(const u16x8*)(wdt + (size_t)is_[k]*D_IN + i0);
#pragma unroll
    for (int j=0;j<8;j++) acc[j] = fmaf(v, bf2f(wv[j]), acc[j]);
  }
  float* xo = xhat + (size_t)n*D_IN + i0;
  f32x4 o0 = {acc[0],acc[1],acc[2],acc[3]};
  f32x4 o1 = {acc[4],acc[5],acc[6],acc[7]};
  ((f32x4*)xo)[0] = o0; ((f32x4*)xo)[1] = o1;
  const float* xr = x + (size_t)n*D_IN + i0;
  float sq = 0.f;
#pragma unroll
  for (int j=0;j<8;j++){ float d = acc[j] - xr[j]; sq = fmaf(d,d,sq); }
  red[t] = sq; __syncthreads();
  for (int s=128;s>0;s>>=1){ if (t<s) red[t] += red[t+s]; __syncthreads(); }
  if (t==0) part[n] = (double)red[0];
}

__global__ void k_loss(const double* __restrict__ part, float* __restrict__ out){
  __shared__ double red[256];
  const int t = threadIdx.x;
  double a = 0.0;
  for (int i=t;i<NROWS;i+=256) a += part[i];
  red[t] = a; __syncthreads();
  for (int s=128;s>0;s>>=1){ if (t<s) red[t]+=red[t+s]; __syncthreads(); }
  if (t==0) out[0] = (float)(red[0] / (double)((size_t)NROWS * D_IN));
}

// ---------------- launch ----------------
extern "C" void kernel_launch(void* const* d_in, const int* in_sizes, int n_in,
                              void* d_out, int out_size, void* d_ws, size_t ws_size,
                              hipStream_t stream)
{
  const float* x     = (const float*)d_in[0];
  const float* W_enc = (const float*)d_in[1];
  const float* b_enc = (const float*)d_in[2];
  const float* W_dec = (const float*)d_in[3];
  const float* b_dec = (const float*)d_in[4];

  float* xhat = (float*)d_out;
  float* h    = xhat + (size_t)NROWS*D_IN;
  float* loss = h + (size_t)NROWS*D_SAE;

  char* ws = (char*)d_ws;
  unsigned short* xbf   = (unsigned short*)(ws);                 // 16 MB
  unsigned short* wencb = (unsigned short*)(ws + 16777216);      // 128 MB
  unsigned short* wdt   = (unsigned short*)(ws + 150994944);     // 128 MB
  float* cv  = (float*) (ws + 285212672);                        // 4 MB
  int*   ci  = (int*)   (ws + 289406976);                        // 4 MB
  int*   cc  = (int*)   (ws + 293601280);                        // 16 KB
  float* sv  = (float*) (ws + 293617664);                        // 1 MB
  int*   si  = (int*)   (ws + 294666240);                        // 1 MB
  double* part = (double*)(ws + 295714816);                      // 32 KB

  k_conv_x   <<<dim3(8192),     dim3(256), 0, stream>>>(x, b_dec, xbf);
  k_conv_w   <<<dim3(65536),    dim3(256), 0, stream>>>(W_enc, wencb);
  k_transpose<<<dim3(1024,64),  dim3(256), 0, stream>>>(W_dec, wdt);
  k_gemm     <<<dim3(256,32),   dim3(256), 0, stream>>>(xbf, wencb, b_enc, h); // pre_acts -> h region
  k_topk     <<<dim3(4096),     dim3(256), 0, stream>>>(h, cv, ci, cc);
  k_rescore  <<<dim3(4096),     dim3(256), 0, stream>>>(x, b_dec, W_enc, b_enc, ci, cc, sv, si);
  k_zero     <<<dim3(131072),   dim3(256), 0, stream>>>((f32x4*)h);
  k_scatter  <<<dim3(1024),     dim3(256), 0, stream>>>(sv, si, h);
  k_decode   <<<dim3(4096),     dim3(256), 0, stream>>>(sv, si, wdt, b_dec, x, xhat, part);
  k_loss     <<<dim3(1),        dim3(256), 0, stream>>>(part, loss);
}

// Round 2
// 1729.763 us; speedup vs baseline: 1.2851x; 1.2851x over previous
//
#include <hip/hip_runtime.h>
#include <stdint.h>

#define D_IN   2048
#define D_SAE  32768
#define NROWS  4096
#define TOPK   64
#define CAND_CAP 256
#define CAND_TARGET 100

typedef __attribute__((ext_vector_type(4))) float f32x4;
typedef __attribute__((ext_vector_type(8))) short short8;
typedef __attribute__((ext_vector_type(4))) unsigned short u16x4;
typedef __attribute__((ext_vector_type(8))) unsigned short u16x8;

__device__ __forceinline__ unsigned short f2bf(float f){
  unsigned int u = __float_as_uint(f);
  u = (u + 0x7FFFu + ((u >> 16) & 1u)) >> 16;   // RNE
  return (unsigned short)u;
}
__device__ __forceinline__ float bf2f(unsigned short h){
  return __uint_as_float(((unsigned int)h) << 16);
}
__device__ __forceinline__ void async16(const unsigned short* g, unsigned short* l){
  __builtin_amdgcn_global_load_lds(
      (const __attribute__((address_space(1))) unsigned int*)g,
      (__attribute__((address_space(3))) unsigned int*)l,
      16, 0, 0);
}

// ---------------- prep: conversions + transpose ----------------
__global__ void k_conv_x(const float* __restrict__ x, const float* __restrict__ b_dec,
                         unsigned short* __restrict__ o){
  const int i = blockIdx.x*256 + threadIdx.x;            // f4 index, 2097152 total
  const f32x4 v = ((const f32x4*)x)[i];
  const f32x4 b = ((const f32x4*)b_dec)[i & (D_IN/4 - 1)];
  u16x4 r;
#pragma unroll
  for (int j=0;j<4;j++) r[j] = f2bf(v[j]-b[j]);
  ((u16x4*)o)[i] = r;
}

__global__ void k_conv_w(const float* __restrict__ wsrc, unsigned short* __restrict__ o){
  const int i = blockIdx.x*256 + threadIdx.x;            // 16777216 total
  const f32x4 v = ((const f32x4*)wsrc)[i];
  u16x4 r;
#pragma unroll
  for (int j=0;j<4;j++) r[j] = f2bf(v[j]);
  ((u16x4*)o)[i] = r;
}

__global__ void k_transpose(const float* __restrict__ wdec, unsigned short* __restrict__ wdt){
  __shared__ float tile[32][33];
  const int j0 = blockIdx.x*32;   // d_sae
  const int i0 = blockIdx.y*32;   // d_in
  const int r = threadIdx.x >> 5, c = threadIdx.x & 31;
#pragma unroll
  for (int a=0;a<4;a++) tile[r+8*a][c] = wdec[(size_t)(i0+r+8*a)*D_SAE + j0 + c];
  __syncthreads();
#pragma unroll
  for (int a=0;a<4;a++) wdt[(size_t)(j0+r+8*a)*D_IN + i0 + c] = f2bf(tile[c][r+8*a]);
}

// ---------------- encoder GEMM (bf16 MFMA, m97 structure, bf16 out) ----------------
// Cb[4096][32768] = bf16( A[4096][2048] * B[32768][2048]^T + b_enc )
__global__ void __launch_bounds__(256) k_gemm(
    const unsigned short* __restrict__ A,
    const unsigned short* __restrict__ B,
    const float* __restrict__ b_enc,
    unsigned short* __restrict__ Cb)
{
  __shared__ unsigned short As[128*32];
  __shared__ unsigned short Bs[128*32];
  const int tid = threadIdx.x;
  const int w = tid >> 6, l = tid & 63;
  const int bm = blockIdx.y, bn = blockIdx.x;
  const size_t brow = (size_t)bm*128, bcol = (size_t)bn*128;
  const int wr = w >> 1, wc = w & 1;       // 2x2 waves, 64x64 each
  const int srow = tid >> 2;               // staging row 0..63 (+64 chunk 1)
  const int skk  = (tid & 3) * 8;          // staging k offset (bf16 elems)
  const int fr = l & 15, fq = l >> 4;
  f32x4 acc[4][4] = {};
  const unsigned short* Ab = A + (brow + srow)*D_IN + skk;
  const unsigned short* Bb = B + (bcol + srow)*D_IN + skk;
  for (int kt = 0; kt < D_IN; kt += 32){
    __syncthreads();
    async16(Ab + kt,                 &As[w*512]);
    async16(Ab + (size_t)64*D_IN+kt, &As[2048 + w*512]);
    async16(Bb + kt,                 &Bs[w*512]);
    async16(Bb + (size_t)64*D_IN+kt, &Bs[2048 + w*512]);
    __syncthreads();
    short8 af[4], bf[4];
#pragma unroll
    for (int m=0;m<4;m++) af[m] = *(const short8*)&As[(wr*64 + m*16 + fr)*32 + fq*8];
#pragma unroll
    for (int n=0;n<4;n++) bf[n] = *(const short8*)&Bs[(wc*64 + n*16 + fr)*32 + fq*8];
#pragma unroll
    for (int m=0;m<4;m++)
#pragma unroll
      for (int n=0;n<4;n++)
        asm("v_mfma_f32_16x16x32_bf16 %0, %1, %2, %0" : "+v"(acc[m][n]) : "v"(af[m]), "v"(bf[n]));
  }
  asm volatile("s_nop 7\n\ts_nop 7" ::: "memory");   // MFMA->VALU read hazard insurance
#pragma unroll
  for (int n=0;n<4;n++){
    const size_t col = bcol + wc*64 + n*16 + fr;
    const float be = b_enc[col];
#pragma unroll
    for (int m=0;m<4;m++){
      const size_t row0 = brow + wr*64 + m*16 + fq*4;
#pragma unroll
      for (int r=0;r<4;r++)
        Cb[(row0 + r)*D_SAE + col] = f2bf(acc[m][n][r] + be);
    }
  }
}

// ---------------- per-row candidate filter (histogram top-~100, bf16 in) ----------------
__global__ void __launch_bounds__(256) k_topk(
    const unsigned short* __restrict__ P,
    int* __restrict__ ci, int* __restrict__ cnt)
{
  __shared__ unsigned int hist[1024];
  __shared__ unsigned int tsuf[256];
  __shared__ int sbin;
  __shared__ unsigned int wcnt;
  const int n = blockIdx.x, t = threadIdx.x;
  for (int i=t;i<1024;i+=256) hist[i]=0u;
  if (t==0){ sbin = 0; wcnt = 0u; }
  __syncthreads();
  const u16x8* row = (const u16x8*)(P + (size_t)n * D_SAE);
#pragma unroll 4
  for (int i=0;i<16;i++){
    u16x8 v = row[t + 256*i];
#pragma unroll
    for (int j=0;j<8;j++){
      float f = bf2f(v[j]);
      if (f > 0.f){
        int b = (int)(f * 64.f); if (b > 1023) b = 1023;
        atomicAdd(&hist[b], 1u);
      }
    }
  }
  __syncthreads();
  const unsigned int h0=hist[4*t+0],h1=hist[4*t+1],h2=hist[4*t+2],h3=hist[4*t+3];
  tsuf[t] = h0+h1+h2+h3;
  __syncthreads();
  for (int off=1; off<256; off<<=1){           // inclusive suffix scan
    unsigned int v = tsuf[t] + ((t+off<256)? tsuf[t+off] : 0u);
    __syncthreads();
    tsuf[t] = v;
    __syncthreads();
  }
  const unsigned int nxt = (t<255)? tsuf[t+1] : 0u;
  const unsigned int s3 = h3 + nxt, s2 = h2+s3, s1 = h1+s2, s0 = h0+s1;
  int best = -1;
  if      (s3 >= CAND_TARGET) best = 4*t+3;
  else if (s2 >= CAND_TARGET) best = 4*t+2;
  else if (s1 >= CAND_TARGET) best = 4*t+1;
  else if (s0 >= CAND_TARGET) best = 4*t+0;
  if (best >= 0) atomicMax(&sbin, best);
  __syncthreads();
  const int bT = sbin;
#pragma unroll 4
  for (int i=0;i<16;i++){
    u16x8 v = row[t + 256*i];
#pragma unroll
    for (int j=0;j<8;j++){
      float f = bf2f(v[j]);
      if (f > 0.f){
        int b = (int)(f * 64.f); if (b > 1023) b = 1023;
        if (b >= bT){
          unsigned int pos = atomicAdd(&wcnt, 1u);
          if (pos < CAND_CAP)
            ci[(size_t)n*CAND_CAP + pos] = (t + 256*i)*8 + j;
        }
      }
    }
  }
  __syncthreads();
  if (t==0) cnt[n] = (int)(wcnt < CAND_CAP ? wcnt : CAND_CAP);
}

// ---------------- exact f32 rescore + top-64 select ----------------
__global__ void __launch_bounds__(256) k_rescore(
    const float* __restrict__ x, const float* __restrict__ b_dec,
    const float* __restrict__ W, const float* __restrict__ b_enc,
    const int* __restrict__ ci, const int* __restrict__ cnt,
    float* __restrict__ sv, int* __restrict__ si)
{
  __shared__ f32x4 xa[D_IN/4];      // 8 KB
  __shared__ float ex[CAND_CAP];
  __shared__ int   exi[CAND_CAP];
  const int n = blockIdx.x, t = threadIdx.x, w = t>>6, l = t&63;
  {
    const f32x4* xr = (const f32x4*)(x + (size_t)n*D_IN);
    const f32x4* br = (const f32x4*)b_dec;
    for (int i=t;i<D_IN/4;i+=256){
      f32x4 v = xr[i], b = br[i];
      f32x4 d; d[0]=v[0]-b[0]; d[1]=v[1]-b[1]; d[2]=v[2]-b[2]; d[3]=v[3]-b[3];
      xa[i] = d;
    }
  }
  for (int i=t;i<CAND_CAP;i+=256){ ex[i] = -1.0e30f; exi[i] = 0x7FFFFFFF; }
  const int cn0 = cnt[n];
  const int cn = cn0 < CAND_CAP ? cn0 : CAND_CAP;
  __syncthreads();
  // 2 candidates in flight per wave, float4 loads, unrolled inner loop
  for (int c0 = w*2; c0 < cn; c0 += 8){
    const int c1 = c0 + 1;
    const int i0 = ci[(size_t)n*CAND_CAP + c0];
    const int i1 = (c1 < cn) ? ci[(size_t)n*CAND_CAP + c1] : i0;
    const f32x4* w0 = (const f32x4*)(W + (size_t)i0*D_IN);
    const f32x4* w1 = (const f32x4*)(W + (size_t)i1*D_IN);
    f32x4 a0 = {0.f,0.f,0.f,0.f}, a1 = {0.f,0.f,0.f,0.f};
#pragma unroll
    for (int e=0;e<8;e++){
      const int p = l + e*64;
      const f32x4 xv = xa[p];
      const f32x4 wv0 = w0[p];
      const f32x4 wv1 = w1[p];
#pragma unroll
      for (int j=0;j<4;j++) a0[j] = fmaf(xv[j], wv0[j], a0[j]);
#pragma unroll
      for (int j=0;j<4;j++) a1[j] = fmaf(xv[j], wv1[j], a1[j]);
    }
    float s0 = (a0[0]+a0[1]) + (a0[2]+a0[3]);
    float s1 = (a1[0]+a1[1]) + (a1[2]+a1[3]);
#pragma unroll
    for (int off=32; off>0; off>>=1){
      s0 += __shfl_down(s0, off);
      s1 += __shfl_down(s1, off);
    }
    if (l==0){
      ex[c0] = s0 + b_enc[i0]; exi[c0] = i0;
      if (c1 < cn){ ex[c1] = s1 + b_enc[i1]; exi[c1] = i1; }
    }
  }
  __syncthreads();
  if (w==0){
    for (int k=0;k<TOPK;k++){
      float bv = -2.0e30f; int bi = 0x7FFFFFFF; int bp = -1;
      for (int c=l; c<cn; c+=64){
        float v = ex[c]; int idx = exi[c];
        if (v > bv || (v == bv && idx < bi)){ bv = v; bi = idx; bp = c; }
      }
#pragma unroll
      for (int off=32; off>0; off>>=1){
        float ov = __shfl_down(bv, off);
        int   oi = __shfl_down(bi, off);
        int   op = __shfl_down(bp, off);
        if (ov > bv || (ov == bv && oi < bi)){ bv=ov; bi=oi; bp=op; }
      }
      bv = __shfl(bv, 0); bi = __shfl(bi, 0); bp = __shfl(bp, 0);
      if (l==0){
        sv[(size_t)n*TOPK + k] = (bp>=0) ? bv : 0.f;
        si[(size_t)n*TOPK + k] = (bp>=0) ? bi : 0;
        if (bp>=0) ex[bp] = -3.0e30f;
      }
    }
  }
}

// ---------------- h output: zero + scatter ----------------
__global__ void k_zero(f32x4* __restrict__ p){
  const size_t i = (size_t)blockIdx.x*256 + threadIdx.x;
  f32x4 z = {0.f,0.f,0.f,0.f};
  p[i] = z;
}
__global__ void k_scatter(const float* __restrict__ sv, const int* __restrict__ si,
                          float* __restrict__ h){
  const int t = blockIdx.x*256 + threadIdx.x;   // 262144
  const int n = t >> 6;
  const float v = sv[t];
  h[(size_t)n*D_SAE + si[t]] = v > 0.f ? v : 0.f;
}

// ---------------- sparse decode + per-row loss partial ----------------
__global__ void __launch_bounds__(256) k_decode(
    const float* __restrict__ sv, const int* __restrict__ si,
    const unsigned short* __restrict__ wdt, const float* __restrict__ b_dec,
    const float* __restrict__ x, float* __restrict__ xhat, double* __restrict__ part)
{
  __shared__ float vs[TOPK];
  __shared__ int   is_[TOPK];
  __shared__ float red[256];
  const int n = blockIdx.x, t = threadIdx.x;
  if (t < TOPK){
    float v = sv[(size_t)n*TOPK + t];
    vs[t] = v > 0.f ? v : 0.f;
    is_[t] = si[(size_t)n*TOPK + t];
  }
  __syncthreads();
  const int i0 = t*8;
  float acc[8];
#pragma unroll
  for (int j=0;j<8;j++) acc[j] = b_dec[i0+j];
  for (int k=0;k<TOPK;k++){
    const float v = vs[k];
    const u16x8 wv = *(const u16x8*)(wdt + (size_t)is_[k]*D_IN + i0);
#pragma unroll
    for (int j=0;j<8;j++) acc[j] = fmaf(v, bf2f(wv[j]), acc[j]);
  }
  float* xo = xhat + (size_t)n*D_IN + i0;
  f32x4 o0 = {acc[0],acc[1],acc[2],acc[3]};
  f32x4 o1 = {acc[4],acc[5],acc[6],acc[7]};
  ((f32x4*)xo)[0] = o0; ((f32x4*)xo)[1] = o1;
  const float* xr = x + (size_t)n*D_IN + i0;
  float sq = 0.f;
#pragma unroll
  for (int j=0;j<8;j++){ float d = acc[j] - xr[j]; sq = fmaf(d,d,sq); }
  red[t] = sq; __syncthreads();
  for (int s=128;s>0;s>>=1){ if (t<s) red[t] += red[t+s]; __syncthreads(); }
  if (t==0) part[n] = (double)red[0];
}

__global__ void k_loss(const double* __restrict__ part, float* __restrict__ out){
  __shared__ double red[256];
  const int t = threadIdx.x;
  double a = 0.0;
  for (int i=t;i<NROWS;i+=256) a += part[i];
  red[t] = a; __syncthreads();
  for (int s=128;s>0;s>>=1){ if (t<s) red[t]+=red[t+s]; __syncthreads(); }
  if (t==0) out[0] = (float)(red[0] / (double)((size_t)NROWS * D_IN));
}

// ---------------- launch ----------------
extern "C" void kernel_launch(void* const* d_in, const int* in_sizes, int n_in,
                              void* d_out, int out_size, void* d_ws, size_t ws_size,
                              hipStream_t stream)
{
  const float* x     = (const float*)d_in[0];
  const float* W_enc = (const float*)d_in[1];
  const float* b_enc = (const float*)d_in[2];
  const float* W_dec = (const float*)d_in[3];
  const float* b_dec = (const float*)d_in[4];

  float* xhat = (float*)d_out;
  float* h    = xhat + (size_t)NROWS*D_IN;
  float* loss = h + (size_t)NROWS*D_SAE;
  unsigned short* pre_bf = (unsigned short*)h;   // bf16 pre_acts staged in h region

  char* ws = (char*)d_ws;
  unsigned short* xbf   = (unsigned short*)(ws);                 // 16 MB
  unsigned short* wencb = (unsigned short*)(ws + 16777216);      // 128 MB
  unsigned short* wdt   = (unsigned short*)(ws + 150994944);     // 128 MB
  int*   ci  = (int*)   (ws + 285212672);                        // 4 MB
  int*   cc  = (int*)   (ws + 289406976);                        // 16 KB
  float* sv  = (float*) (ws + 289423360);                        // 1 MB
  int*   si  = (int*)   (ws + 290471936);                        // 1 MB
  double* part = (double*)(ws + 291520512);                      // 32 KB

  k_conv_x   <<<dim3(8192),     dim3(256), 0, stream>>>(x, b_dec, xbf);
  k_conv_w   <<<dim3(65536),    dim3(256), 0, stream>>>(W_enc, wencb);
  k_transpose<<<dim3(1024,64),  dim3(256), 0, stream>>>(W_dec, wdt);
  k_gemm     <<<dim3(256,32),   dim3(256), 0, stream>>>(xbf, wencb, b_enc, pre_bf);
  k_topk     <<<dim3(4096),     dim3(256), 0, stream>>>(pre_bf, ci, cc);
  k_rescore  <<<dim3(4096),     dim3(256), 0, stream>>>(x, b_dec, W_enc, b_enc, ci, cc, sv, si);
  k_zero     <<<dim3(131072),   dim3(256), 0, stream>>>((f32x4*)h);
  k_scatter  <<<dim3(1024),     dim3(256), 0, stream>>>(sv, si, h);
  k_decode   <<<dim3(4096),     dim3(256), 0, stream>>>(sv, si, wdt, b_dec, x, xhat, part);
  k_loss     <<<dim3(1),        dim3(256), 0, stream>>>(part, loss);
}